// Round 3
// baseline (3134.404 us; speedup 1.0000x reference)
//
#include <hip/hip_runtime.h>
#include <cmath>

#define T_STEPS 8
#define NN 50000
#define EE 800000

typedef unsigned short ushort_t;
typedef __attribute__((ext_vector_type(8))) short s16x8;
typedef __attribute__((ext_vector_type(4))) float f32x4;

__device__ __forceinline__ float sigf(float x){ return 1.f/(1.f + __expf(-x)); }
__device__ __forceinline__ float tanhfast(float x){ return 1.f - 2.f/(1.f + __expf(2.f*x)); }

__device__ __forceinline__ ushort_t bf16_rne(float f){
    unsigned u = __float_as_uint(f);
    unsigned r = (u + 0x7fffu + ((u >> 16) & 1u)) >> 16;
    return (ushort_t)r;
}
__device__ __forceinline__ float bf16f(ushort_t h){ return __uint_as_float(((unsigned)h) << 16); }

// ---- Build weight fragments: Bh/Bl[ ((ks*16+nt)*64 + lane)*8 + e ] ----
// Wcat[k][col]: k-blocks = [x|Tx0|Tx1|Tx2], col = gate*64 + cc.
// Frag mapping (mfma_f32_16x16x32_bf16 B operand): k = ks*32 + (lane>>4)*8 + e, col = nt*16 + (lane&15).
__global__ void k_build_wfrag(const float* __restrict__ Wx, const float* __restrict__ Th,
                              const float* __restrict__ b, ushort_t* __restrict__ Bh,
                              ushort_t* __restrict__ Bl, float* __restrict__ bcat){
    int idx = blockIdx.x*blockDim.x + threadIdx.x;
    if (idx >= 256*256) return;
    int e    = idx & 7;
    int lane = (idx >> 3) & 63;
    int nt   = (idx >> 9) & 15;
    int ks   = idx >> 13;
    int k    = ks*32 + (lane >> 4)*8 + e;
    int col  = nt*16 + (lane & 15);
    int g = col >> 6, cc = col & 63, kb = k >> 6, kk = k & 63;
    float v = (kb == 0) ? Wx[(g*64 + kk)*64 + cc]
                        : Th[((g*3 + (kb-1))*64 + kk)*64 + cc];
    ushort_t hb = bf16_rne(v);
    float lo = v - bf16f(hb);
    Bh[idx] = hb;
    Bl[idx] = bf16_rne(lo);
    if (idx < 256) bcat[idx] = b[idx];
}

// ---- degree (by src) + histogram (by dst), one edge pass ----
__global__ void k_deg_hist(const int* __restrict__ src, const int* __restrict__ dst,
                           const float* __restrict__ w, float* __restrict__ deg,
                           int* __restrict__ cnt, int E){
    int e = blockIdx.x*blockDim.x + threadIdx.x;
    if (e < E){
        unsafeAtomicAdd(&deg[src[e]], w[e]);
        atomicAdd(&cnt[dst[e]], 1);
    }
}

// ---- scan stage 1 (+ dinv fused: deg is ready) ----
__global__ void k_scan1(const int* __restrict__ cnt, const float* __restrict__ deg,
                        float* __restrict__ dinv, int* __restrict__ part,
                        int* __restrict__ bsum, int N){
    __shared__ int s[256];
    int i = blockIdx.x*256 + threadIdx.x;
    int v = (i < N) ? cnt[i] : 0;
    s[threadIdx.x] = v; __syncthreads();
    #pragma unroll
    for (int off = 1; off < 256; off <<= 1){
        int t = (threadIdx.x >= off) ? s[threadIdx.x - off] : 0;
        __syncthreads();
        s[threadIdx.x] += t;
        __syncthreads();
    }
    if (i < N){
        part[i] = s[threadIdx.x] - v;
        float d = deg[i];
        dinv[i] = d > 0.f ? rsqrtf(fmaxf(d, 1e-12f)) : 0.f;
    }
    if (threadIdx.x == 255) bsum[blockIdx.x] = s[255];
}

__global__ void k_scan2(int* __restrict__ bsum, int nb){
    __shared__ int s[256];
    int i = threadIdx.x;
    int v = (i < nb) ? bsum[i] : 0;
    s[i] = v; __syncthreads();
    #pragma unroll
    for (int off = 1; off < 256; off <<= 1){
        int t = (i >= off) ? s[i - off] : 0;
        __syncthreads();
        s[i] += t;
        __syncthreads();
    }
    if (i < nb) bsum[i] = s[i] - v;
}

__global__ void k_scan3(const int* __restrict__ part, const int* __restrict__ bsum,
                        int* __restrict__ row_start, int* __restrict__ cursor, int N, int E){
    int i = blockIdx.x*256 + threadIdx.x;
    if (i < N){
        int v = part[i] + bsum[blockIdx.x];
        row_start[i] = v;
        cursor[i]    = v;
    }
    if (i == 0) row_start[N] = E;
}

// ---- permute edges into CSR order + compute norm inline; pack (src, nrm) ----
__global__ void k_perm(const int* __restrict__ src, const int* __restrict__ dst,
                       const float* __restrict__ w, const float* __restrict__ dinv,
                       int* __restrict__ cursor, int2* __restrict__ edat, int E){
    int e = blockIdx.x*blockDim.x + threadIdx.x;
    if (e < E){
        int s = src[e], d = dst[e];
        float nr = -dinv[s] * w[e] * dinv[d];
        int p = atomicAdd(&cursor[d], 1);
        edat[p] = make_int2(s, __float_as_int(nr));
    }
}

// ---- gather SpMV: out[n] = scale * sum_j nrm[j]*X[src[j]] ; 16 threads/node x float4 ----
__global__ __launch_bounds__(256) void k_spmv_g(
        const int* __restrict__ row_start, const int2* __restrict__ edat,
        const float* __restrict__ X, float* __restrict__ outb, int N, float scale){
    int gid = blockIdx.x*blockDim.x + threadIdx.x;
    int n = gid >> 4;
    if (n >= N) return;
    int q = (gid & 15) << 2;
    int j = row_start[n], end = row_start[n+1];
    float4 acc = make_float4(0.f,0.f,0.f,0.f);
    for (; j + 1 < end; j += 2){
        int2 e0 = edat[j], e1 = edat[j+1];
        float s0 = __int_as_float(e0.y), s1 = __int_as_float(e1.y);
        const float4 v0 = *reinterpret_cast<const float4*>(X + (size_t)e0.x*64 + q);
        const float4 v1 = *reinterpret_cast<const float4*>(X + (size_t)e1.x*64 + q);
        acc.x += s0*v0.x + s1*v1.x;
        acc.y += s0*v0.y + s1*v1.y;
        acc.z += s0*v0.z + s1*v1.z;
        acc.w += s0*v0.w + s1*v1.w;
    }
    if (j < end){
        int2 e0 = edat[j];
        float s0 = __int_as_float(e0.y);
        const float4 v0 = *reinterpret_cast<const float4*>(X + (size_t)e0.x*64 + q);
        acc.x += s0*v0.x; acc.y += s0*v0.y; acc.z += s0*v0.z; acc.w += s0*v0.w;
    }
    acc.x *= scale; acc.y *= scale; acc.z *= scale; acc.w *= scale;
    *reinterpret_cast<float4*>(outb + (size_t)n*64 + q) = acc;
}

// ---- fused MFMA GEMM (split-bf16, fp32-quality) + LSTM gate epilogue ----
// Block: 64 rows x 256 cols, 4 waves; wave w owns rows 16w..16w+15.
// A = [x | H | Tx1 | S2-H] (N x 256), split hi/lo bf16, staged in LDS.
// B frags pre-packed in per-lane order (Bh/Bl), loaded straight from L2.
#define LDSA 264   // 256 + 8 pad (bf16 elems per row; 528B stride -> 2-way bank = free)
__global__ __launch_bounds__(256, 2) void k_gemm_mfma(
        const float* __restrict__ x, float* __restrict__ H,
        const float* __restrict__ Tx1, const float* __restrict__ S2,
        const ushort_t* __restrict__ Bh, const ushort_t* __restrict__ Bl,
        const float* __restrict__ bcat, const float* __restrict__ wc,
        float* __restrict__ C, float* __restrict__ out, int N, int last){
    __shared__ ushort_t Ah[64*LDSA];
    __shared__ ushort_t Al[64*LDSA];
    const int t  = threadIdx.x;
    const int bm = blockIdx.x * 64;

    // ---- stage A hi/lo (coalesced: 4 threads per row, 16 floats each) ----
    {
        const int row = t >> 2;
        const int kq  = t & 3;
        const int n   = bm + row;
        for (int kt = 0; kt < 4; ++kt){
            const float* sp = (kt==0) ? x : (kt==1) ? H : (kt==2) ? Tx1 : S2;
            #pragma unroll
            for (int j = 0; j < 4; ++j){
                const int k = kq*16 + j*4;     // 0..63 within this kt block
                float4 v = make_float4(0.f,0.f,0.f,0.f);
                if (n < N){
                    v = *reinterpret_cast<const float4*>(sp + (size_t)n*64 + k);
                    if (kt == 3){
                        float4 h = *reinterpret_cast<const float4*>(H + (size_t)n*64 + k);
                        v.x -= h.x; v.y -= h.y; v.z -= h.z; v.w -= h.w;
                    }
                }
                float vv[4] = {v.x, v.y, v.z, v.w};
                ushort_t h4[4], l4[4];
                #pragma unroll
                for (int e2 = 0; e2 < 4; ++e2){
                    ushort_t hb = bf16_rne(vv[e2]);
                    h4[e2] = hb;
                    l4[e2] = bf16_rne(vv[e2] - bf16f(hb));
                }
                const int ko = kt*64 + k;
                *reinterpret_cast<ushort4*>(&Ah[row*LDSA + ko]) = make_ushort4(h4[0],h4[1],h4[2],h4[3]);
                *reinterpret_cast<ushort4*>(&Al[row*LDSA + ko]) = make_ushort4(l4[0],l4[1],l4[2],l4[3]);
            }
        }
    }
    __syncthreads();

    // ---- MFMA main loop ----
    const int w  = t >> 6;        // wave 0..3
    const int l  = t & 63;
    const int lr = l & 15;
    const int lg = l >> 4;        // 0..3
    f32x4 acc[16];
    #pragma unroll
    for (int i = 0; i < 16; ++i) acc[i] = (f32x4){0.f,0.f,0.f,0.f};

    const int arow = w*16 + lr;   // A row (M) this lane supplies
    for (int ks = 0; ks < 8; ++ks){
        const int koff = ks*32 + lg*8;
        s16x8 ah = *reinterpret_cast<const s16x8*>(&Ah[arow*LDSA + koff]);
        s16x8 al = *reinterpret_cast<const s16x8*>(&Al[arow*LDSA + koff]);
        #pragma unroll 4
        for (int nt = 0; nt < 16; ++nt){
            const size_t fo = ((size_t)(ks*16 + nt)*64 + l)*8;
            s16x8 bh = *reinterpret_cast<const s16x8*>(Bh + fo);
            s16x8 bl = *reinterpret_cast<const s16x8*>(Bl + fo);
            acc[nt] = __builtin_amdgcn_mfma_f32_16x16x32_bf16(ah, bh, acc[nt], 0, 0, 0);
            acc[nt] = __builtin_amdgcn_mfma_f32_16x16x32_bf16(ah, bl, acc[nt], 0, 0, 0);
            acc[nt] = __builtin_amdgcn_mfma_f32_16x16x32_bf16(al, bh, acc[nt], 0, 0, 0);
        }
    }

    // ---- LSTM gate epilogue (lane-local: D col=lane&15, row=(lane>>4)*4+r) ----
    // acc[nt=4*g+cq][r] = z_g at (row = bm+16w+4*lg+r, c = lr+16*cq)
    const int rbase = bm + w*16 + lg*4;
    #pragma unroll
    for (int cq = 0; cq < 4; ++cq){
        const int c = lr + 16*cq;
        const float b0 = bcat[c], b1 = bcat[64+c], b2 = bcat[128+c], b3 = bcat[192+c];
        const float w0 = wc[c], w1 = wc[64+c], w2v = wc[128+c];
        #pragma unroll
        for (int r = 0; r < 4; ++r){
            const int rowi = rbase + r;
            if (rowi >= N) continue;
            const size_t idx = (size_t)rowi*64 + c;
            const float cold = C[idx];
            const float z0 = acc[cq][r]     + b0;
            const float z1 = acc[4+cq][r]   + b1;
            const float z2 = acc[8+cq][r]   + b2;
            const float z3 = acc[12+cq][r]  + b3;
            const float i_ = sigf(z0 + w0*cold);
            const float f_ = sigf(z1 + w1*cold);
            const float g_ = tanhfast(z2);
            const float cn = f_*cold + i_*g_;
            const float o_ = sigf(z3 + w2v*cn);
            const float hn = o_*tanhfast(cn);
            C[idx] = cn;
            H[idx] = hn;
            if (last) out[idx] = fmaxf(hn, 0.f);
        }
    }
}

extern "C" void kernel_launch(void* const* d_in, const int* in_sizes, int n_in,
                              void* d_out, int out_size, void* d_ws, size_t ws_size,
                              hipStream_t stream){
    const float* x_seq = (const float*)d_in[0];
    const float* w_seq = (const float*)d_in[1];
    const float* Wx    = (const float*)d_in[2];
    const float* Th    = (const float*)d_in[3];
    const float* b     = (const float*)d_in[4];
    const float* wc    = (const float*)d_in[5];
    const int*   ei    = (const int*)d_in[6];
    float* out = (float*)d_out;

    float* ws = (float*)d_ws;
    size_t off = 0;
    float* H        = ws + off; off += (size_t)NN*64;
    float* C        = ws + off; off += (size_t)NN*64;
    float* Tx1      = ws + off; off += (size_t)NN*64;
    float* S2       = ws + off; off += (size_t)NN*64;
    float* deg      = ws + off; off += NN;            // deg + cnt contiguous (one memset)
    int*   cnt      = (int*)(ws + off); off += NN;
    float* dinv     = ws + off; off += NN;
    int*   part     = (int*)(ws + off); off += NN;
    int*   bsum     = (int*)(ws + off); off += 256;
    int*   row_start= (int*)(ws + off); off += NN + 1;
    int*   cursor   = (int*)(ws + off); off += NN;
    int2*  edat     = (int2*)(ws + off); off += (size_t)EE*2;
    ushort_t* Bh    = (ushort_t*)(ws + off); off += 256*256/2;
    ushort_t* Bl    = (ushort_t*)(ws + off); off += 256*256/2;
    float* bcat     = ws + off; off += 256;

    const int NB = (NN + 255)/256;

    hipMemsetAsync(H, 0, (size_t)NN*64*2*sizeof(float), stream);
    k_build_wfrag<<<256, 256, 0, stream>>>(Wx, Th, b, Bh, Bl, bcat);

    for (int t = 0; t < T_STEPS; ++t){
        const int* src = ei + (size_t)t*2*EE;
        const int* dst = src + EE;
        const float* w = w_seq + (size_t)t*EE;
        const float* x = x_seq + (size_t)t*NN*64;

        hipMemsetAsync(deg, 0, NN*2*sizeof(float), stream);   // deg + cnt
        k_deg_hist<<<(EE+255)/256, 256, 0, stream>>>(src, dst, w, deg, cnt, EE);
        k_scan1<<<NB, 256, 0, stream>>>(cnt, deg, dinv, part, bsum, NN);
        k_scan2<<<1, 256, 0, stream>>>(bsum, NB);
        k_scan3<<<NB, 256, 0, stream>>>(part, bsum, row_start, cursor, NN, EE);
        k_perm <<<(EE+255)/256, 256, 0, stream>>>(src, dst, w, dinv, cursor, edat, EE);

        k_spmv_g<<<(NN*16+255)/256, 256, 0, stream>>>(row_start, edat, H,   Tx1, NN, 1.0f);
        k_spmv_g<<<(NN*16+255)/256, 256, 0, stream>>>(row_start, edat, Tx1, S2,  NN, 2.0f);

        k_gemm_mfma<<<(NN+63)/64, 256, 0, stream>>>(x, H, Tx1, S2, Bh, Bl, bcat, wc,
                                                    C, out, NN, t==T_STEPS-1);
    }
}

// Round 4
// 2198.156 us; speedup vs baseline: 1.4259x; 1.4259x over previous
//
#include <hip/hip_runtime.h>
#include <cmath>

#define T_STEPS 8
#define NN 50000
#define EE 800000

typedef unsigned short ushort_t;
typedef __attribute__((ext_vector_type(8))) short s16x8;
typedef __attribute__((ext_vector_type(4))) float f32x4;

__device__ __forceinline__ float sigf(float x){ return 1.f/(1.f + __expf(-x)); }
__device__ __forceinline__ float tanhfast(float x){ return 1.f - 2.f/(1.f + __expf(2.f*x)); }

__device__ __forceinline__ ushort_t bf16_rne(float f){
    unsigned u = __float_as_uint(f);
    unsigned r = (u + 0x7fffu + ((u >> 16) & 1u)) >> 16;
    return (ushort_t)r;
}
__device__ __forceinline__ float bf16f(ushort_t h){ return __uint_as_float(((unsigned)h) << 16); }

// ---- Build weight fragments: Bh/Bl[ ((ks*16+nt)*64 + lane)*8 + e ] ----
// Frag mapping (mfma B operand): k = ks*32 + (lane>>4)*8 + e, col = nt*16 + (lane&15).
__global__ void k_build_wfrag(const float* __restrict__ Wx, const float* __restrict__ Th,
                              const float* __restrict__ b, ushort_t* __restrict__ Bh,
                              ushort_t* __restrict__ Bl, float* __restrict__ bcat){
    int idx = blockIdx.x*blockDim.x + threadIdx.x;
    if (idx >= 256*256) return;
    int e    = idx & 7;
    int lane = (idx >> 3) & 63;
    int nt   = (idx >> 9) & 15;
    int ks   = idx >> 13;
    int k    = ks*32 + (lane >> 4)*8 + e;
    int col  = nt*16 + (lane & 15);
    int g = col >> 6, cc = col & 63, kb = k >> 6, kk = k & 63;
    float v = (kb == 0) ? Wx[(g*64 + kk)*64 + cc]
                        : Th[((g*3 + (kb-1))*64 + kk)*64 + cc];
    ushort_t hb = bf16_rne(v);
    float lo = v - bf16f(hb);
    Bh[idx] = hb;
    Bl[idx] = bf16_rne(lo);
    if (idx < 256) bcat[idx] = b[idx];
}

// ---- degree (by src) + histogram (by dst), one edge pass ----
__global__ void k_deg_hist(const int* __restrict__ src, const int* __restrict__ dst,
                           const float* __restrict__ w, float* __restrict__ deg,
                           int* __restrict__ cnt, int E){
    int e = blockIdx.x*blockDim.x + threadIdx.x;
    if (e < E){
        unsafeAtomicAdd(&deg[src[e]], w[e]);
        atomicAdd(&cnt[dst[e]], 1);
    }
}

__global__ void k_scan1(const int* __restrict__ cnt, const float* __restrict__ deg,
                        float* __restrict__ dinv, int* __restrict__ part,
                        int* __restrict__ bsum, int N){
    __shared__ int s[256];
    int i = blockIdx.x*256 + threadIdx.x;
    int v = (i < N) ? cnt[i] : 0;
    s[threadIdx.x] = v; __syncthreads();
    #pragma unroll
    for (int off = 1; off < 256; off <<= 1){
        int t = (threadIdx.x >= off) ? s[threadIdx.x - off] : 0;
        __syncthreads();
        s[threadIdx.x] += t;
        __syncthreads();
    }
    if (i < N){
        part[i] = s[threadIdx.x] - v;
        float d = deg[i];
        dinv[i] = d > 0.f ? rsqrtf(fmaxf(d, 1e-12f)) : 0.f;
    }
    if (threadIdx.x == 255) bsum[blockIdx.x] = s[255];
}

__global__ void k_scan2(int* __restrict__ bsum, int nb){
    __shared__ int s[256];
    int i = threadIdx.x;
    int v = (i < nb) ? bsum[i] : 0;
    s[i] = v; __syncthreads();
    #pragma unroll
    for (int off = 1; off < 256; off <<= 1){
        int t = (i >= off) ? s[i - off] : 0;
        __syncthreads();
        s[i] += t;
        __syncthreads();
    }
    if (i < nb) bsum[i] = s[i] - v;
}

__global__ void k_scan3(const int* __restrict__ part, const int* __restrict__ bsum,
                        int* __restrict__ row_start, int* __restrict__ cursor, int N, int E){
    int i = blockIdx.x*256 + threadIdx.x;
    if (i < N){
        int v = part[i] + bsum[blockIdx.x];
        row_start[i] = v;
        cursor[i]    = v;
    }
    if (i == 0) row_start[N] = E;
}

__global__ void k_perm(const int* __restrict__ src, const int* __restrict__ dst,
                       const float* __restrict__ w, const float* __restrict__ dinv,
                       int* __restrict__ cursor, int2* __restrict__ edat, int E){
    int e = blockIdx.x*blockDim.x + threadIdx.x;
    if (e < E){
        int s = src[e], d = dst[e];
        float nr = -dinv[s] * w[e] * dinv[d];
        int p = atomicAdd(&cursor[d], 1);
        edat[p] = make_int2(s, __float_as_int(nr));
    }
}

// ---- gather SpMV ----
__global__ __launch_bounds__(256) void k_spmv_g(
        const int* __restrict__ row_start, const int2* __restrict__ edat,
        const float* __restrict__ X, float* __restrict__ outb, int N, float scale){
    int gid = blockIdx.x*blockDim.x + threadIdx.x;
    int n = gid >> 4;
    if (n >= N) return;
    int q = (gid & 15) << 2;
    int j = row_start[n], end = row_start[n+1];
    float4 acc = make_float4(0.f,0.f,0.f,0.f);
    for (; j + 1 < end; j += 2){
        int2 e0 = edat[j], e1 = edat[j+1];
        float s0 = __int_as_float(e0.y), s1 = __int_as_float(e1.y);
        const float4 v0 = *reinterpret_cast<const float4*>(X + (size_t)e0.x*64 + q);
        const float4 v1 = *reinterpret_cast<const float4*>(X + (size_t)e1.x*64 + q);
        acc.x += s0*v0.x + s1*v1.x;
        acc.y += s0*v0.y + s1*v1.y;
        acc.z += s0*v0.z + s1*v1.z;
        acc.w += s0*v0.w + s1*v1.w;
    }
    if (j < end){
        int2 e0 = edat[j];
        float s0 = __int_as_float(e0.y);
        const float4 v0 = *reinterpret_cast<const float4*>(X + (size_t)e0.x*64 + q);
        acc.x += s0*v0.x; acc.y += s0*v0.y; acc.z += s0*v0.z; acc.w += s0*v0.w;
    }
    acc.x *= scale; acc.y *= scale; acc.z *= scale; acc.w *= scale;
    *reinterpret_cast<float4*>(outb + (size_t)n*64 + q) = acc;
}

// ---- fused MFMA GEMM (split-bf16) + LSTM epilogue; no LDS, fully unrolled ----
// Block: 64 rows x 256 cols, 4 waves; wave w owns rows 16w..16w+15 (zero A reuse
// across waves -> no LDS). A-frag loads are cacheline-coalesced: lanes
// {lr,lr+16,lr+32,lr+48} fetch the 4 x 32B quarters of one 128B line.
__global__ __launch_bounds__(256) void k_gemm_mfma(
        const float* __restrict__ x, float* __restrict__ H,
        const float* __restrict__ Tx1, const float* __restrict__ S2,
        const ushort_t* __restrict__ Bh, const ushort_t* __restrict__ Bl,
        const float* __restrict__ bcat, const float* __restrict__ wc,
        float* __restrict__ C, float* __restrict__ out, int N, int last){
    const int t  = threadIdx.x;
    const int w  = t >> 6;
    const int l  = t & 63;
    const int lr = l & 15;
    const int lg = l >> 4;
    const int bm = blockIdx.x * 64;
    const int arow = bm + w*16 + lr;
    const bool valid = arow < N;

    f32x4 acc[16];
    #pragma unroll
    for (int i = 0; i < 16; ++i) acc[i] = (f32x4){0.f,0.f,0.f,0.f};

    #pragma unroll
    for (int ks = 0; ks < 8; ++ks){
        const int kt = ks >> 1;                 // compile-time after unroll
        const int kk = (ks & 1)*32 + lg*8;      // col within the kt 64-block
        const float* sp = (kt==0) ? x : (kt==1) ? H : (kt==2) ? Tx1 : S2;
        float va[8];
        if (valid){
            const float4 v0 = *reinterpret_cast<const float4*>(sp + (size_t)arow*64 + kk);
            const float4 v1 = *reinterpret_cast<const float4*>(sp + (size_t)arow*64 + kk + 4);
            va[0]=v0.x; va[1]=v0.y; va[2]=v0.z; va[3]=v0.w;
            va[4]=v1.x; va[5]=v1.y; va[6]=v1.z; va[7]=v1.w;
            if (kt == 3){   // Tx2 = S2 - H
                const float4 h0 = *reinterpret_cast<const float4*>(H + (size_t)arow*64 + kk);
                const float4 h1 = *reinterpret_cast<const float4*>(H + (size_t)arow*64 + kk + 4);
                va[0]-=h0.x; va[1]-=h0.y; va[2]-=h0.z; va[3]-=h0.w;
                va[4]-=h1.x; va[5]-=h1.y; va[6]-=h1.z; va[7]-=h1.w;
            }
        } else {
            #pragma unroll
            for (int e = 0; e < 8; ++e) va[e] = 0.f;
        }
        // truncation-based hi/lo split (rel err ~2^-16, 4 ops/elem)
        s16x8 ah, al;
        #pragma unroll
        for (int e = 0; e < 8; ++e){
            const unsigned u = __float_as_uint(va[e]);
            const ushort_t hb = (ushort_t)(u >> 16);
            const float lo = va[e] - bf16f(hb);
            ah[e] = (short)hb;
            al[e] = (short)(ushort_t)(__float_as_uint(lo) >> 16);
        }
        const ushort_t* bph = Bh + ((size_t)(ks*16)*64 + l)*8;
        const ushort_t* bpl = Bl + ((size_t)(ks*16)*64 + l)*8;
        #pragma unroll
        for (int nt = 0; nt < 16; ++nt){
            const s16x8 bh = *reinterpret_cast<const s16x8*>(bph + (size_t)nt*64*8);
            const s16x8 bl = *reinterpret_cast<const s16x8*>(bpl + (size_t)nt*64*8);
            acc[nt] = __builtin_amdgcn_mfma_f32_16x16x32_bf16(ah, bh, acc[nt], 0, 0, 0);
            acc[nt] = __builtin_amdgcn_mfma_f32_16x16x32_bf16(ah, bl, acc[nt], 0, 0, 0);
            acc[nt] = __builtin_amdgcn_mfma_f32_16x16x32_bf16(al, bh, acc[nt], 0, 0, 0);
        }
    }

    // ---- LSTM gate epilogue (D layout: col=lane&15, row=(lane>>4)*4+r) ----
    const int rbase = bm + w*16 + lg*4;
    #pragma unroll
    for (int cq = 0; cq < 4; ++cq){
        const int c = lr + 16*cq;
        const float b0 = bcat[c], b1 = bcat[64+c], b2 = bcat[128+c], b3 = bcat[192+c];
        const float w0 = wc[c], w1 = wc[64+c], w2v = wc[128+c];
        #pragma unroll
        for (int r = 0; r < 4; ++r){
            const int rowi = rbase + r;
            if (rowi >= N) continue;
            const size_t idx = (size_t)rowi*64 + c;
            const float cold = C[idx];
            const float z0 = acc[cq][r]     + b0;
            const float z1 = acc[4+cq][r]   + b1;
            const float z2 = acc[8+cq][r]   + b2;
            const float z3 = acc[12+cq][r]  + b3;
            const float i_ = sigf(z0 + w0*cold);
            const float f_ = sigf(z1 + w1*cold);
            const float g_ = tanhfast(z2);
            const float cn = f_*cold + i_*g_;
            const float o_ = sigf(z3 + w2v*cn);
            const float hn = o_*tanhfast(cn);
            C[idx] = cn;
            H[idx] = hn;
            if (last) out[idx] = fmaxf(hn, 0.f);
        }
    }
}

extern "C" void kernel_launch(void* const* d_in, const int* in_sizes, int n_in,
                              void* d_out, int out_size, void* d_ws, size_t ws_size,
                              hipStream_t stream){
    const float* x_seq = (const float*)d_in[0];
    const float* w_seq = (const float*)d_in[1];
    const float* Wx    = (const float*)d_in[2];
    const float* Th    = (const float*)d_in[3];
    const float* b     = (const float*)d_in[4];
    const float* wc    = (const float*)d_in[5];
    const int*   ei    = (const int*)d_in[6];
    float* out = (float*)d_out;

    float* ws = (float*)d_ws;
    size_t off = 0;
    float* H        = ws + off; off += (size_t)NN*64;
    float* C        = ws + off; off += (size_t)NN*64;
    float* Tx1      = ws + off; off += (size_t)NN*64;
    float* S2       = ws + off; off += (size_t)NN*64;
    float* deg      = ws + off; off += NN;            // deg + cnt contiguous (one memset)
    int*   cnt      = (int*)(ws + off); off += NN;
    float* dinv     = ws + off; off += NN;
    int*   part     = (int*)(ws + off); off += NN;
    int*   bsum     = (int*)(ws + off); off += 256;
    int*   row_start= (int*)(ws + off); off += NN + 1;
    int*   cursor   = (int*)(ws + off); off += NN;
    int2*  edat     = (int2*)(ws + off); off += (size_t)EE*2;
    ushort_t* Bh    = (ushort_t*)(ws + off); off += 256*256/2;
    ushort_t* Bl    = (ushort_t*)(ws + off); off += 256*256/2;
    float* bcat     = ws + off; off += 256;

    const int NB = (NN + 255)/256;

    hipMemsetAsync(H, 0, (size_t)NN*64*2*sizeof(float), stream);
    k_build_wfrag<<<256, 256, 0, stream>>>(Wx, Th, b, Bh, Bl, bcat);

    for (int t = 0; t < T_STEPS; ++t){
        const int* src = ei + (size_t)t*2*EE;
        const int* dst = src + EE;
        const float* w = w_seq + (size_t)t*EE;
        const float* x = x_seq + (size_t)t*NN*64;

        hipMemsetAsync(deg, 0, NN*2*sizeof(float), stream);   // deg + cnt
        k_deg_hist<<<(EE+255)/256, 256, 0, stream>>>(src, dst, w, deg, cnt, EE);
        k_scan1<<<NB, 256, 0, stream>>>(cnt, deg, dinv, part, bsum, NN);
        k_scan2<<<1, 256, 0, stream>>>(bsum, NB);
        k_scan3<<<NB, 256, 0, stream>>>(part, bsum, row_start, cursor, NN, EE);
        k_perm <<<(EE+255)/256, 256, 0, stream>>>(src, dst, w, dinv, cursor, edat, EE);

        k_spmv_g<<<(NN*16+255)/256, 256, 0, stream>>>(row_start, edat, H,   Tx1, NN, 1.0f);
        k_spmv_g<<<(NN*16+255)/256, 256, 0, stream>>>(row_start, edat, Tx1, S2,  NN, 2.0f);

        k_gemm_mfma<<<(NN+63)/64, 256, 0, stream>>>(x, H, Tx1, S2, Bh, Bl, bcat, wc,
                                                    C, out, NN, t==T_STEPS-1);
    }
}

// Round 5
// 1681.834 us; speedup vs baseline: 1.8637x; 1.3070x over previous
//
#include <hip/hip_runtime.h>
#include <cmath>

#define T_STEPS 8
#define NN 50000
#define EE 800000

typedef unsigned short ushort_t;
typedef __attribute__((ext_vector_type(8))) short s16x8;
typedef __attribute__((ext_vector_type(4))) float f32x4;

__device__ __forceinline__ float sigf(float x){ return 1.f/(1.f + __expf(-x)); }
__device__ __forceinline__ float tanhfast(float x){ return 1.f - 2.f/(1.f + __expf(2.f*x)); }

__device__ __forceinline__ ushort_t bf16_rne(float f){
    unsigned u = __float_as_uint(f);
    unsigned r = (u + 0x7fffu + ((u >> 16) & 1u)) >> 16;
    return (ushort_t)r;
}
__device__ __forceinline__ float bf16f(ushort_t h){ return __uint_as_float(((unsigned)h) << 16); }

__device__ __forceinline__ void gload_lds16(const void* g, void* l){
    __builtin_amdgcn_global_load_lds((const __attribute__((address_space(1))) void*)g,
                                     (__attribute__((address_space(3))) void*)l, 16, 0, 0);
}

// ---- Build weight fragments: Bh/Bl[ ((ks*16+nt)*64 + lane)*8 + e ] ----
// k = ks*32 + (lane>>4)*8 + e, col = nt*16 + (lane&15). ks-slice (16KB) contiguous.
__global__ void k_build_wfrag(const float* __restrict__ Wx, const float* __restrict__ Th,
                              const float* __restrict__ b, ushort_t* __restrict__ Bh,
                              ushort_t* __restrict__ Bl, float* __restrict__ bcat){
    int idx = blockIdx.x*blockDim.x + threadIdx.x;
    if (idx >= 256*256) return;
    int e    = idx & 7;
    int lane = (idx >> 3) & 63;
    int nt   = (idx >> 9) & 15;
    int ks   = idx >> 13;
    int k    = ks*32 + (lane >> 4)*8 + e;
    int col  = nt*16 + (lane & 15);
    int g = col >> 6, cc = col & 63, kb = k >> 6, kk = k & 63;
    float v = (kb == 0) ? Wx[(g*64 + kk)*64 + cc]
                        : Th[((g*3 + (kb-1))*64 + kk)*64 + cc];
    ushort_t hb = bf16_rne(v);
    float lo = v - bf16f(hb);
    Bh[idx] = hb;
    Bl[idx] = bf16_rne(lo);
    if (idx < 256) bcat[idx] = b[idx];
}

// ---- batched graph prep (grid.y = tt within chunk of TB steps) ----
__global__ void k_deg_hist(const int* __restrict__ ei, const float* __restrict__ wseq,
                           int t0, float* __restrict__ deg8, int* __restrict__ cnt8){
    int e = blockIdx.x*blockDim.x + threadIdx.x;
    if (e >= EE) return;
    int tt = blockIdx.y;
    int t  = t0 + tt;
    const int* src = ei + (size_t)t*2*EE;
    const int* dst = src + EE;
    unsafeAtomicAdd(&deg8[(size_t)tt*NN + src[e]], wseq[(size_t)t*EE + e]);
    atomicAdd(&cnt8[(size_t)tt*NN + dst[e]], 1);
}

__global__ void k_scan1(const int* __restrict__ cnt8, const float* __restrict__ deg8,
                        float* __restrict__ dinv8, int* __restrict__ part8,
                        int* __restrict__ bsum8){
    __shared__ int s[256];
    int tt = blockIdx.y;
    int i = blockIdx.x*256 + threadIdx.x;
    int v = (i < NN) ? cnt8[(size_t)tt*NN + i] : 0;
    s[threadIdx.x] = v; __syncthreads();
    #pragma unroll
    for (int off = 1; off < 256; off <<= 1){
        int t = (threadIdx.x >= off) ? s[threadIdx.x - off] : 0;
        __syncthreads();
        s[threadIdx.x] += t;
        __syncthreads();
    }
    if (i < NN){
        part8[(size_t)tt*NN + i] = s[threadIdx.x] - v;
        float d = deg8[(size_t)tt*NN + i];
        dinv8[(size_t)tt*NN + i] = d > 0.f ? rsqrtf(fmaxf(d, 1e-12f)) : 0.f;
    }
    if (threadIdx.x == 255) bsum8[tt*256 + blockIdx.x] = s[255];
}

__global__ void k_scan2(int* __restrict__ bsum8, int nb){
    __shared__ int s[256];
    int tt = blockIdx.x;
    int i = threadIdx.x;
    int v = (i < nb) ? bsum8[tt*256 + i] : 0;
    s[i] = v; __syncthreads();
    #pragma unroll
    for (int off = 1; off < 256; off <<= 1){
        int t = (i >= off) ? s[i - off] : 0;
        __syncthreads();
        s[i] += t;
        __syncthreads();
    }
    if (i < nb) bsum8[tt*256 + i] = s[i] - v;
}

__global__ void k_scan3(const int* __restrict__ part8, const int* __restrict__ bsum8,
                        int* __restrict__ row_start8, int* __restrict__ cursor8){
    int tt = blockIdx.y;
    int i = blockIdx.x*256 + threadIdx.x;
    if (i < NN){
        int v = part8[(size_t)tt*NN + i] + bsum8[tt*256 + blockIdx.x];
        row_start8[(size_t)tt*(NN+1) + i] = v;
        cursor8[(size_t)tt*NN + i]        = v;
    }
    if (i == 0) row_start8[(size_t)tt*(NN+1) + NN] = EE;
}

__global__ void k_perm(const int* __restrict__ ei, const float* __restrict__ wseq,
                       int t0, const float* __restrict__ dinv8,
                       int* __restrict__ cursor8, int2* __restrict__ edat8){
    int e = blockIdx.x*blockDim.x + threadIdx.x;
    if (e >= EE) return;
    int tt = blockIdx.y;
    int t  = t0 + tt;
    const int* src = ei + (size_t)t*2*EE;
    const int* dst = src + EE;
    int s = src[e], d = dst[e];
    float nr = -dinv8[(size_t)tt*NN + s] * wseq[(size_t)t*EE + e] * dinv8[(size_t)tt*NN + d];
    int p = atomicAdd(&cursor8[(size_t)tt*NN + d], 1);
    edat8[(size_t)tt*EE + p] = make_int2(s, __float_as_int(nr));
}

// ---- gather SpMV: out[n] = scale*sum_j nrm*X[src] (- Hs[n] if sub) ----
__global__ __launch_bounds__(256) void k_spmv_g(
        const int* __restrict__ row_start, const int2* __restrict__ edat,
        const float* __restrict__ X, const float* __restrict__ Hs,
        float* __restrict__ outb, int N, float scale, int sub){
    int gid = blockIdx.x*blockDim.x + threadIdx.x;
    int n = gid >> 4;
    if (n >= N) return;
    int q = (gid & 15) << 2;
    int j = row_start[n], end = row_start[n+1];
    float4 acc = make_float4(0.f,0.f,0.f,0.f);
    for (; j + 4 <= end; j += 4){
        int2 ea = edat[j], eb = edat[j+1], ec = edat[j+2], ed = edat[j+3];
        const float4 v0 = *reinterpret_cast<const float4*>(X + (size_t)ea.x*64 + q);
        const float4 v1 = *reinterpret_cast<const float4*>(X + (size_t)eb.x*64 + q);
        const float4 v2 = *reinterpret_cast<const float4*>(X + (size_t)ec.x*64 + q);
        const float4 v3 = *reinterpret_cast<const float4*>(X + (size_t)ed.x*64 + q);
        float sa = __int_as_float(ea.y), sb = __int_as_float(eb.y);
        float sc = __int_as_float(ec.y), sd = __int_as_float(ed.y);
        acc.x += sa*v0.x + sb*v1.x + sc*v2.x + sd*v3.x;
        acc.y += sa*v0.y + sb*v1.y + sc*v2.y + sd*v3.y;
        acc.z += sa*v0.z + sb*v1.z + sc*v2.z + sd*v3.z;
        acc.w += sa*v0.w + sb*v1.w + sc*v2.w + sd*v3.w;
    }
    for (; j < end; ++j){
        int2 e0 = edat[j];
        float s0 = __int_as_float(e0.y);
        const float4 v0 = *reinterpret_cast<const float4*>(X + (size_t)e0.x*64 + q);
        acc.x += s0*v0.x; acc.y += s0*v0.y; acc.z += s0*v0.z; acc.w += s0*v0.w;
    }
    float4 r;
    if (sub){
        const float4 h = *reinterpret_cast<const float4*>(Hs + (size_t)n*64 + q);
        r.x = scale*acc.x - h.x; r.y = scale*acc.y - h.y;
        r.z = scale*acc.z - h.z; r.w = scale*acc.w - h.w;
    } else {
        r.x = scale*acc.x; r.y = scale*acc.y; r.z = scale*acc.z; r.w = scale*acc.w;
    }
    *reinterpret_cast<float4*>(outb + (size_t)n*64 + q) = r;
}

// ---- fused MFMA GEMM (split-bf16) + LSTM epilogue; B double-buffered in LDS ----
// Block = 64 rows x 256 cols, 4 waves (wave w: rows 16w..16w+15).
// B slices (K=32 x N=256, hi+lo = 32KB) staged via global_load_lds, dbuf.
__global__ __launch_bounds__(256) void k_gemm_mfma(
        const float* __restrict__ x, float* __restrict__ H,
        const float* __restrict__ Tx1, const float* __restrict__ Tx2,
        const ushort_t* __restrict__ Bh, const ushort_t* __restrict__ Bl,
        const float* __restrict__ bcat, const float* __restrict__ wc,
        float* __restrict__ C, float* __restrict__ out, int N, int last){
    __shared__ ushort_t Bs[2][2][8192];   // [buf][hi/lo][16KB]
    const int t  = threadIdx.x;
    const int w  = t >> 6;
    const int l  = t & 63;
    const int lr = l & 15;
    const int lg = l >> 4;
    const int bm = blockIdx.x * 64;
    const int arow = bm + w*16 + lr;
    const bool valid = arow < N;
    const float* const srcs[4] = {x, H, Tx1, Tx2};

    f32x4 acc[16];
    #pragma unroll
    for (int i = 0; i < 16; ++i) acc[i] = (f32x4){0.f,0.f,0.f,0.f};

    // stage B slice ks into buf: each wave covers 4 chunks of 1KB per hi/lo
    #define STAGE(ks_, buf_) {                                                   \
        const size_t sl = (size_t)(ks_)*8192;                                    \
        _Pragma("unroll")                                                        \
        for (int c = 0; c < 4; ++c){                                             \
            const int ch = (w*4 + c)*512;                                        \
            gload_lds16(Bh + sl + ch + l*8, &Bs[buf_][0][ch]);                   \
            gload_lds16(Bl + sl + ch + l*8, &Bs[buf_][1][ch]);                   \
        }                                                                        \
    }

    float4 va0, va1, na0, na1;
    // prologue: stage slice 0, load A(ks=0)
    STAGE(0, 0);
    {
        const int kk = lg*8;
        if (valid){
            va0 = *reinterpret_cast<const float4*>(x + (size_t)arow*64 + kk);
            va1 = *reinterpret_cast<const float4*>(x + (size_t)arow*64 + kk + 4);
        } else { va0 = va1 = make_float4(0.f,0.f,0.f,0.f); }
    }

    #pragma unroll
    for (int ks = 0; ks < 8; ++ks){
        const int buf = ks & 1;
        __syncthreads();   // hipcc drains vmcnt/lgkmcnt here: slice ks + A(ks) complete
        if (ks < 7){
            STAGE(ks+1, buf^1);
            const int kt = (ks+1) >> 1;
            const int kk = ((ks+1) & 1)*32 + lg*8;
            const float* sp = srcs[kt];
            if (valid){
                na0 = *reinterpret_cast<const float4*>(sp + (size_t)arow*64 + kk);
                na1 = *reinterpret_cast<const float4*>(sp + (size_t)arow*64 + kk + 4);
            } else { na0 = na1 = make_float4(0.f,0.f,0.f,0.f); }
        }
        // build A frags (truncation hi/lo split)
        float va[8] = {va0.x, va0.y, va0.z, va0.w, va1.x, va1.y, va1.z, va1.w};
        s16x8 ah, al;
        #pragma unroll
        for (int e = 0; e < 8; ++e){
            const unsigned u = __float_as_uint(va[e]);
            const ushort_t hb = (ushort_t)(u >> 16);
            const float lo = va[e] - bf16f(hb);
            ah[e] = (short)hb;
            al[e] = (short)(ushort_t)(__float_as_uint(lo) >> 16);
        }
        #pragma unroll
        for (int nt = 0; nt < 16; ++nt){
            const s16x8 bh = *reinterpret_cast<const s16x8*>(&Bs[buf][0][(nt*64 + l)*8]);
            const s16x8 bl = *reinterpret_cast<const s16x8*>(&Bs[buf][1][(nt*64 + l)*8]);
            acc[nt] = __builtin_amdgcn_mfma_f32_16x16x32_bf16(ah, bh, acc[nt], 0, 0, 0);
            acc[nt] = __builtin_amdgcn_mfma_f32_16x16x32_bf16(ah, bl, acc[nt], 0, 0, 0);
            acc[nt] = __builtin_amdgcn_mfma_f32_16x16x32_bf16(al, bh, acc[nt], 0, 0, 0);
        }
        va0 = na0; va1 = na1;
    }
    #undef STAGE

    // ---- LSTM gate epilogue (D layout: col=lane&15, row=(lane>>4)*4+r) ----
    const int rbase = bm + w*16 + lg*4;
    #pragma unroll
    for (int cq = 0; cq < 4; ++cq){
        const int c = lr + 16*cq;
        const float b0 = bcat[c], b1 = bcat[64+c], b2 = bcat[128+c], b3 = bcat[192+c];
        const float w0 = wc[c], w1 = wc[64+c], w2v = wc[128+c];
        #pragma unroll
        for (int r = 0; r < 4; ++r){
            const int rowi = rbase + r;
            if (rowi >= N) continue;
            const size_t idx = (size_t)rowi*64 + c;
            const float cold = C[idx];
            const float z0 = acc[cq][r]     + b0;
            const float z1 = acc[4+cq][r]   + b1;
            const float z2 = acc[8+cq][r]   + b2;
            const float z3 = acc[12+cq][r]  + b3;
            const float i_ = sigf(z0 + w0*cold);
            const float f_ = sigf(z1 + w1*cold);
            const float g_ = tanhfast(z2);
            const float cn = f_*cold + i_*g_;
            const float o_ = sigf(z3 + w2v*cn);
            const float hn = o_*tanhfast(cn);
            C[idx] = cn;
            H[idx] = hn;
            if (last) out[idx] = fmaxf(hn, 0.f);
        }
    }
}

extern "C" void kernel_launch(void* const* d_in, const int* in_sizes, int n_in,
                              void* d_out, int out_size, void* d_ws, size_t ws_size,
                              hipStream_t stream){
    const float* x_seq = (const float*)d_in[0];
    const float* w_seq = (const float*)d_in[1];
    const float* Wx    = (const float*)d_in[2];
    const float* Th    = (const float*)d_in[3];
    const float* b     = (const float*)d_in[4];
    const float* wc    = (const float*)d_in[5];
    const int*   ei    = (const int*)d_in[6];
    float* out = (float*)d_out;

    float* ws = (float*)d_ws;
    size_t off = 0;   // in floats
    float* H    = ws + off; off += (size_t)NN*64;
    float* C    = ws + off; off += (size_t)NN*64;
    float* Tx1  = ws + off; off += (size_t)NN*64;
    float* Tx2  = ws + off; off += (size_t)NN*64;
    ushort_t* Bh = (ushort_t*)(ws + off); off += 256*256/2;
    ushort_t* Bl = (ushort_t*)(ws + off); off += 256*256/2;
    float* bcat = ws + off; off += 256;

    // adaptive: batch all 8 steps' graph prep if workspace allows
    const size_t per_t_floats = (size_t)EE*2       // edat
                              + (size_t)NN*6 + 1   // deg,cnt,dinv,part,cursor,row_start(+1)
                              + 256 + 8;           // bsum + pad
    const size_t need8 = (off + 8*per_t_floats) * sizeof(float);
    const int TB = (ws_size >= need8) ? 8 : 1;

    int2*  edat8      = (int2*)(ws + off); off += (size_t)TB*EE*2;
    float* deg8       = ws + off;          off += (size_t)TB*NN;
    int*   cnt8       = (int*)(ws + off);  off += (size_t)TB*NN;
    float* dinv8      = ws + off;          off += (size_t)TB*NN;
    int*   part8      = (int*)(ws + off);  off += (size_t)TB*NN;
    int*   cursor8    = (int*)(ws + off);  off += (size_t)TB*NN;
    int*   row_start8 = (int*)(ws + off);  off += (size_t)TB*(NN+1);
    int*   bsum8      = (int*)(ws + off);  off += (size_t)TB*256;

    const int NB = (NN + 255)/256;
    const int EB = (EE + 255)/256;

    hipMemsetAsync(H, 0, (size_t)NN*64*2*sizeof(float), stream);
    k_build_wfrag<<<256, 256, 0, stream>>>(Wx, Th, b, Bh, Bl, bcat);

    auto prep = [&](int t0){
        hipMemsetAsync(deg8, 0, (size_t)TB*NN*2*sizeof(float), stream);  // deg8+cnt8 adjacent
        k_deg_hist<<<dim3(EB, TB), 256, 0, stream>>>(ei, w_seq, t0, deg8, cnt8);
        k_scan1<<<dim3(NB, TB), 256, 0, stream>>>(cnt8, deg8, dinv8, part8, bsum8);
        k_scan2<<<TB, 256, 0, stream>>>(bsum8, NB);
        k_scan3<<<dim3(NB, TB), 256, 0, stream>>>(part8, bsum8, row_start8, cursor8);
        k_perm<<<dim3(EB, TB), 256, 0, stream>>>(ei, w_seq, t0, dinv8, cursor8, edat8);
    };

    if (TB == 8) prep(0);

    for (int t = 0; t < T_STEPS; ++t){
        if (TB == 1) prep(t);
        const int tt = (TB == 8) ? t : 0;
        const int* rs = row_start8 + (size_t)tt*(NN+1);
        const int2* ed = edat8 + (size_t)tt*EE;
        const float* x = x_seq + (size_t)t*NN*64;

        k_spmv_g<<<(NN*16+255)/256, 256, 0, stream>>>(rs, ed, H,   H, Tx1, NN, 1.0f, 0);
        k_spmv_g<<<(NN*16+255)/256, 256, 0, stream>>>(rs, ed, Tx1, H, Tx2, NN, 2.0f, 1);
        k_gemm_mfma<<<(NN+63)/64, 256, 0, stream>>>(x, H, Tx1, Tx2, Bh, Bl, bcat, wc,
                                                    C, out, NN, t==T_STEPS-1);
    }
}

// Round 6
// 1667.458 us; speedup vs baseline: 1.8797x; 1.0086x over previous
//
#include <hip/hip_runtime.h>
#include <cmath>

#define T_STEPS 8
#define NN 50000
#define EE 800000

typedef unsigned short ushort_t;
typedef __attribute__((ext_vector_type(8))) short s16x8;
typedef __attribute__((ext_vector_type(4))) float f32x4;

__device__ __forceinline__ float sigf(float x){ return 1.f/(1.f + __expf(-x)); }
__device__ __forceinline__ float tanhfast(float x){ return 1.f - 2.f/(1.f + __expf(2.f*x)); }

__device__ __forceinline__ ushort_t bf16_rne(float f){
    unsigned u = __float_as_uint(f);
    unsigned r = (u + 0x7fffu + ((u >> 16) & 1u)) >> 16;
    return (ushort_t)r;
}
__device__ __forceinline__ float bf16f(ushort_t h){ return __uint_as_float(((unsigned)h) << 16); }

__device__ __forceinline__ void gload_lds16(const void* g, void* l){
    __builtin_amdgcn_global_load_lds((const __attribute__((address_space(1))) void*)g,
                                     (__attribute__((address_space(3))) void*)l, 16, 0, 0);
}

// ---- Build weight fragments: Bh/Bl[ ((ks*16+nt)*64 + lane)*8 + e ] ----
__global__ void k_build_wfrag(const float* __restrict__ Wx, const float* __restrict__ Th,
                              const float* __restrict__ b, ushort_t* __restrict__ Bh,
                              ushort_t* __restrict__ Bl, float* __restrict__ bcat){
    int idx = blockIdx.x*blockDim.x + threadIdx.x;
    if (idx >= 256*256) return;
    int e    = idx & 7;
    int lane = (idx >> 3) & 63;
    int nt   = (idx >> 9) & 15;
    int ks   = idx >> 13;
    int k    = ks*32 + (lane >> 4)*8 + e;
    int col  = nt*16 + (lane & 15);
    int g = col >> 6, cc = col & 63, kb = k >> 6, kk = k & 63;
    float v = (kb == 0) ? Wx[(g*64 + kk)*64 + cc]
                        : Th[((g*3 + (kb-1))*64 + kk)*64 + cc];
    ushort_t hb = bf16_rne(v);
    float lo = v - bf16f(hb);
    Bh[idx] = hb;
    Bl[idx] = bf16_rne(lo);
    if (idx < 256) bcat[idx] = b[idx];
}

// ---- XCD-privatized degree (by src) + histogram (by dst) ----
// copy = blockIdx.x & (NC-1): with round-robin block->XCD dispatch, each copy's
// lines live in ONE XCD's L2 -> atomics are L2-local, no cross-XCD ping-pong.
__global__ void k_deg_hist(const int* __restrict__ ei, const float* __restrict__ wseq,
                           int t0, float* __restrict__ degp, int* __restrict__ cntp,
                           int NC){
    int e = blockIdx.x*blockDim.x + threadIdx.x;
    if (e >= EE) return;
    int tt = blockIdx.y;
    int t  = t0 + tt;
    const int copy = blockIdx.x & (NC-1);
    const int* src = ei + (size_t)t*2*EE;
    const int* dst = src + EE;
    float* dp = degp + ((size_t)tt*NC + copy)*NN;
    int*   cp = cntp + ((size_t)tt*NC + copy)*NN;
    unsafeAtomicAdd(&dp[src[e]], wseq[(size_t)t*EE + e]);
    atomicAdd(&cp[dst[e]], 1);
}

// ---- scan stage 1: reduce copies, dinv, block-local prefix ----
__global__ void k_scan1(const int* __restrict__ cntp, const float* __restrict__ degp,
                        float* __restrict__ dinv8, int* __restrict__ part8,
                        int* __restrict__ bsum8, int NC){
    __shared__ int s[256];
    int tt = blockIdx.y;
    int i = blockIdx.x*256 + threadIdx.x;
    int v = 0;
    float d = 0.f;
    if (i < NN){
        for (int c = 0; c < NC; ++c){
            v += cntp[((size_t)tt*NC + c)*NN + i];
            d += degp[((size_t)tt*NC + c)*NN + i];
        }
    }
    s[threadIdx.x] = v; __syncthreads();
    #pragma unroll
    for (int off = 1; off < 256; off <<= 1){
        int t = (threadIdx.x >= off) ? s[threadIdx.x - off] : 0;
        __syncthreads();
        s[threadIdx.x] += t;
        __syncthreads();
    }
    if (i < NN){
        part8[(size_t)tt*NN + i] = s[threadIdx.x] - v;
        dinv8[(size_t)tt*NN + i] = d > 0.f ? rsqrtf(fmaxf(d, 1e-12f)) : 0.f;
    }
    if (threadIdx.x == 255) bsum8[tt*256 + blockIdx.x] = s[255];
}

__global__ void k_scan2(int* __restrict__ bsum8, int nb){
    __shared__ int s[256];
    int tt = blockIdx.x;
    int i = threadIdx.x;
    int v = (i < nb) ? bsum8[tt*256 + i] : 0;
    s[i] = v; __syncthreads();
    #pragma unroll
    for (int off = 1; off < 256; off <<= 1){
        int t = (i >= off) ? s[i - off] : 0;
        __syncthreads();
        s[i] += t;
        __syncthreads();
    }
    if (i < nb) bsum8[tt*256 + i] = s[i] - v;
}

// ---- scan stage 3: row_start + per-copy cursor bases ----
__global__ void k_scan3(const int* __restrict__ part8, const int* __restrict__ bsum8,
                        const int* __restrict__ cntp, int* __restrict__ row_start8,
                        int* __restrict__ curp, int NC){
    int tt = blockIdx.y;
    int i = blockIdx.x*256 + threadIdx.x;
    if (i < NN){
        int v = part8[(size_t)tt*NN + i] + bsum8[tt*256 + blockIdx.x];
        row_start8[(size_t)tt*(NN+1) + i] = v;
        for (int c = 0; c < NC; ++c){
            const size_t k = ((size_t)tt*NC + c)*NN + i;
            curp[k] = v;
            v += cntp[k];
        }
    }
    if (i == 0) row_start8[(size_t)tt*(NN+1) + NN] = EE;
}

// ---- permute edges into CSR order (XCD-private cursors) ----
__global__ void k_perm(const int* __restrict__ ei, const float* __restrict__ wseq,
                       int t0, const float* __restrict__ dinv8,
                       int* __restrict__ curp, int2* __restrict__ edat8, int NC){
    int e = blockIdx.x*blockDim.x + threadIdx.x;
    if (e >= EE) return;
    int tt = blockIdx.y;
    int t  = t0 + tt;
    const int copy = blockIdx.x & (NC-1);
    const int* src = ei + (size_t)t*2*EE;
    const int* dst = src + EE;
    int s = src[e], d = dst[e];
    float nr = -dinv8[(size_t)tt*NN + s] * wseq[(size_t)t*EE + e] * dinv8[(size_t)tt*NN + d];
    int p = atomicAdd(&curp[((size_t)tt*NC + copy)*NN + d], 1);
    edat8[(size_t)tt*EE + p] = make_int2(s, __float_as_int(nr));
}

// ---- gather SpMV: out[n] = scale*sum_j nrm*X[src] (- Hs[n] if sub) ----
__global__ __launch_bounds__(256) void k_spmv_g(
        const int* __restrict__ row_start, const int2* __restrict__ edat,
        const float* __restrict__ X, const float* __restrict__ Hs,
        float* __restrict__ outb, int N, float scale, int sub){
    int gid = blockIdx.x*blockDim.x + threadIdx.x;
    int n = gid >> 4;
    if (n >= N) return;
    int q = (gid & 15) << 2;
    int j = row_start[n], end = row_start[n+1];
    float4 acc = make_float4(0.f,0.f,0.f,0.f);
    for (; j + 4 <= end; j += 4){
        int2 ea = edat[j], eb = edat[j+1], ec = edat[j+2], ed = edat[j+3];
        const float4 v0 = *reinterpret_cast<const float4*>(X + (size_t)ea.x*64 + q);
        const float4 v1 = *reinterpret_cast<const float4*>(X + (size_t)eb.x*64 + q);
        const float4 v2 = *reinterpret_cast<const float4*>(X + (size_t)ec.x*64 + q);
        const float4 v3 = *reinterpret_cast<const float4*>(X + (size_t)ed.x*64 + q);
        float sa = __int_as_float(ea.y), sb = __int_as_float(eb.y);
        float sc = __int_as_float(ec.y), sd = __int_as_float(ed.y);
        acc.x += sa*v0.x + sb*v1.x + sc*v2.x + sd*v3.x;
        acc.y += sa*v0.y + sb*v1.y + sc*v2.y + sd*v3.y;
        acc.z += sa*v0.z + sb*v1.z + sc*v2.z + sd*v3.z;
        acc.w += sa*v0.w + sb*v1.w + sc*v2.w + sd*v3.w;
    }
    for (; j < end; ++j){
        int2 e0 = edat[j];
        float s0 = __int_as_float(e0.y);
        const float4 v0 = *reinterpret_cast<const float4*>(X + (size_t)e0.x*64 + q);
        acc.x += s0*v0.x; acc.y += s0*v0.y; acc.z += s0*v0.z; acc.w += s0*v0.w;
    }
    float4 r;
    if (sub){
        const float4 h = *reinterpret_cast<const float4*>(Hs + (size_t)n*64 + q);
        r.x = scale*acc.x - h.x; r.y = scale*acc.y - h.y;
        r.z = scale*acc.z - h.z; r.w = scale*acc.w - h.w;
    } else {
        r.x = scale*acc.x; r.y = scale*acc.y; r.z = scale*acc.z; r.w = scale*acc.w;
    }
    *reinterpret_cast<float4*>(outb + (size_t)n*64 + q) = r;
}

// ---- fused MFMA GEMM (split-bf16) + LSTM epilogue; B double-buffered in LDS ----
__global__ __launch_bounds__(256) void k_gemm_mfma(
        const float* __restrict__ x, float* __restrict__ H,
        const float* __restrict__ Tx1, const float* __restrict__ Tx2,
        const ushort_t* __restrict__ Bh, const ushort_t* __restrict__ Bl,
        const float* __restrict__ bcat, const float* __restrict__ wc,
        float* __restrict__ C, float* __restrict__ out, int N, int last){
    __shared__ ushort_t Bs[2][2][8192];   // [buf][hi/lo][16KB]
    const int t  = threadIdx.x;
    const int w  = t >> 6;
    const int l  = t & 63;
    const int lr = l & 15;
    const int lg = l >> 4;
    const int bm = blockIdx.x * 64;
    const int arow = bm + w*16 + lr;
    const bool valid = arow < N;
    const float* const srcs[4] = {x, H, Tx1, Tx2};

    f32x4 acc[16];
    #pragma unroll
    for (int i = 0; i < 16; ++i) acc[i] = (f32x4){0.f,0.f,0.f,0.f};

    #define STAGE(ks_, buf_) {                                                   \
        const size_t sl = (size_t)(ks_)*8192;                                    \
        _Pragma("unroll")                                                        \
        for (int c = 0; c < 4; ++c){                                             \
            const int ch = (w*4 + c)*512;                                        \
            gload_lds16(Bh + sl + ch + l*8, &Bs[buf_][0][ch]);                   \
            gload_lds16(Bl + sl + ch + l*8, &Bs[buf_][1][ch]);                   \
        }                                                                        \
    }

    float4 va0, va1, na0, na1;
    STAGE(0, 0);
    {
        const int kk = lg*8;
        if (valid){
            va0 = *reinterpret_cast<const float4*>(x + (size_t)arow*64 + kk);
            va1 = *reinterpret_cast<const float4*>(x + (size_t)arow*64 + kk + 4);
        } else { va0 = va1 = make_float4(0.f,0.f,0.f,0.f); }
    }

    #pragma unroll
    for (int ks = 0; ks < 8; ++ks){
        const int buf = ks & 1;
        __syncthreads();
        if (ks < 7){
            STAGE(ks+1, buf^1);
            const int kt = (ks+1) >> 1;
            const int kk = ((ks+1) & 1)*32 + lg*8;
            const float* sp = srcs[kt];
            if (valid){
                na0 = *reinterpret_cast<const float4*>(sp + (size_t)arow*64 + kk);
                na1 = *reinterpret_cast<const float4*>(sp + (size_t)arow*64 + kk + 4);
            } else { na0 = na1 = make_float4(0.f,0.f,0.f,0.f); }
        }
        float va[8] = {va0.x, va0.y, va0.z, va0.w, va1.x, va1.y, va1.z, va1.w};
        s16x8 ah, al;
        #pragma unroll
        for (int e = 0; e < 8; ++e){
            const unsigned u = __float_as_uint(va[e]);
            const ushort_t hb = (ushort_t)(u >> 16);
            const float lo = va[e] - bf16f(hb);
            ah[e] = (short)hb;
            al[e] = (short)(ushort_t)(__float_as_uint(lo) >> 16);
        }
        #pragma unroll
        for (int nt = 0; nt < 16; ++nt){
            const s16x8 bh = *reinterpret_cast<const s16x8*>(&Bs[buf][0][(nt*64 + l)*8]);
            const s16x8 bl = *reinterpret_cast<const s16x8*>(&Bs[buf][1][(nt*64 + l)*8]);
            acc[nt] = __builtin_amdgcn_mfma_f32_16x16x32_bf16(ah, bh, acc[nt], 0, 0, 0);
            acc[nt] = __builtin_amdgcn_mfma_f32_16x16x32_bf16(ah, bl, acc[nt], 0, 0, 0);
            acc[nt] = __builtin_amdgcn_mfma_f32_16x16x32_bf16(al, bh, acc[nt], 0, 0, 0);
        }
        va0 = na0; va1 = na1;
    }
    #undef STAGE

    const int rbase = bm + w*16 + lg*4;
    #pragma unroll
    for (int cq = 0; cq < 4; ++cq){
        const int c = lr + 16*cq;
        const float b0 = bcat[c], b1 = bcat[64+c], b2 = bcat[128+c], b3 = bcat[192+c];
        const float w0 = wc[c], w1 = wc[64+c], w2v = wc[128+c];
        #pragma unroll
        for (int r = 0; r < 4; ++r){
            const int rowi = rbase + r;
            if (rowi >= N) continue;
            const size_t idx = (size_t)rowi*64 + c;
            const float cold = C[idx];
            const float z0 = acc[cq][r]     + b0;
            const float z1 = acc[4+cq][r]   + b1;
            const float z2 = acc[8+cq][r]   + b2;
            const float z3 = acc[12+cq][r]  + b3;
            const float i_ = sigf(z0 + w0*cold);
            const float f_ = sigf(z1 + w1*cold);
            const float g_ = tanhfast(z2);
            const float cn = f_*cold + i_*g_;
            const float o_ = sigf(z3 + w2v*cn);
            const float hn = o_*tanhfast(cn);
            C[idx] = cn;
            H[idx] = hn;
            if (last) out[idx] = fmaxf(hn, 0.f);
        }
    }
}

extern "C" void kernel_launch(void* const* d_in, const int* in_sizes, int n_in,
                              void* d_out, int out_size, void* d_ws, size_t ws_size,
                              hipStream_t stream){
    const float* x_seq = (const float*)d_in[0];
    const float* w_seq = (const float*)d_in[1];
    const float* Wx    = (const float*)d_in[2];
    const float* Th    = (const float*)d_in[3];
    const float* b     = (const float*)d_in[4];
    const float* wc    = (const float*)d_in[5];
    const int*   ei    = (const int*)d_in[6];
    float* out = (float*)d_out;

    float* ws = (float*)d_ws;
    size_t off = 0;   // in floats
    float* H    = ws + off; off += (size_t)NN*64;
    float* C    = ws + off; off += (size_t)NN*64;
    float* Tx1  = ws + off; off += (size_t)NN*64;
    float* Tx2  = ws + off; off += (size_t)NN*64;
    ushort_t* Bh = (ushort_t*)(ws + off); off += 256*256/2;
    ushort_t* Bl = (ushort_t*)(ws + off); off += 256*256/2;
    float* bcat = ws + off; off += 256;

    // choose (TB steps batched, NC privatized copies) to fit workspace
    const size_t base_f = off;
    auto need = [&](int TB_, int NC_)->size_t{
        size_t per = (size_t)EE*2                 // edat
                   + (size_t)NC_*NN*3             // degp, cntp, curp
                   + (size_t)NN*2 + (NN+1) + 256; // dinv, part, row_start, bsum
        return (base_f + (size_t)TB_*per + 1024) * sizeof(float);
    };
    int TB = 1, NC = 1;
    const int cfgs[6][2] = {{8,8},{8,4},{8,2},{8,1},{1,8},{1,1}};
    for (int i = 0; i < 6; ++i){
        if (need(cfgs[i][0], cfgs[i][1]) <= ws_size){ TB = cfgs[i][0]; NC = cfgs[i][1]; break; }
    }

    int2*  edat8      = (int2*)(ws + off); off += (size_t)TB*EE*2;
    float* degp       = ws + off;          off += (size_t)TB*NC*NN;
    int*   cntp       = (int*)(ws + off);  off += (size_t)TB*NC*NN;
    int*   curp       = (int*)(ws + off);  off += (size_t)TB*NC*NN;
    float* dinv8      = ws + off;          off += (size_t)TB*NN;
    int*   part8      = (int*)(ws + off);  off += (size_t)TB*NN;
    int*   row_start8 = (int*)(ws + off);  off += (size_t)TB*(NN+1);
    int*   bsum8      = (int*)(ws + off);  off += (size_t)TB*256;

    const int NB = (NN + 255)/256;
    const int EB = (EE + 255)/256;

    hipMemsetAsync(H, 0, (size_t)NN*64*2*sizeof(float), stream);
    k_build_wfrag<<<256, 256, 0, stream>>>(Wx, Th, b, Bh, Bl, bcat);

    auto prep = [&](int t0){
        hipMemsetAsync(degp, 0, (size_t)TB*NC*NN*2*sizeof(float), stream);  // degp+cntp adjacent
        k_deg_hist<<<dim3(EB, TB), 256, 0, stream>>>(ei, w_seq, t0, degp, cntp, NC);
        k_scan1<<<dim3(NB, TB), 256, 0, stream>>>(cntp, degp, dinv8, part8, bsum8, NC);
        k_scan2<<<TB, 256, 0, stream>>>(bsum8, NB);
        k_scan3<<<dim3(NB, TB), 256, 0, stream>>>(part8, bsum8, cntp, row_start8, curp, NC);
        k_perm<<<dim3(EB, TB), 256, 0, stream>>>(ei, w_seq, t0, dinv8, curp, edat8, NC);
    };

    if (TB == 8) prep(0);

    for (int t = 0; t < T_STEPS; ++t){
        if (TB == 1) prep(t);
        const int tt = (TB == 8) ? t : 0;
        const int* rs = row_start8 + (size_t)tt*(NN+1);
        const int2* ed = edat8 + (size_t)tt*EE;
        const float* x = x_seq + (size_t)t*NN*64;

        k_spmv_g<<<(NN*16+255)/256, 256, 0, stream>>>(rs, ed, H,   H, Tx1, NN, 1.0f, 0);
        k_spmv_g<<<(NN*16+255)/256, 256, 0, stream>>>(rs, ed, Tx1, H, Tx2, NN, 2.0f, 1);
        k_gemm_mfma<<<(NN+63)/64, 256, 0, stream>>>(x, H, Tx1, Tx2, Bh, Bl, bcat, wc,
                                                    C, out, NN, t==T_STEPS-1);
    }
}